// Round 8
// baseline (78458.636 us; speedup 1.0000x reference)
//
#include <hip/hip_runtime.h>

typedef __attribute__((ext_vector_type(8))) short short8;
typedef __attribute__((ext_vector_type(4))) float float4_t;
typedef unsigned short u16;
typedef unsigned int u32;
typedef unsigned long long u64;

// B=256, T=256, IN=128, S=1024. Timesteps t=0..255, two GEMM stages per t.
// 4 independent 64-row chains; per wave: slot j (0..1023) = chain j&3, t = j>>2.
// Tagged words (bf16<<16)|tag: u(t) tag=t in ub[t&1]; s1(t) tag=t+1 in sb[t&1].
// NO barriers in the loop: global handoff = tag-polled sc1 words; intra-WG k-split
// reduce = LDS flags (lgkmcnt only — global prefetches stay in flight).

__device__ __forceinline__ u16 f2bf(float f) {
  u32 u = __builtin_bit_cast(u32, f);
  u += 0x7fffu + ((u >> 16) & 1u);          // RNE
  return (u16)(u >> 16);
}
__device__ __forceinline__ float bf2f(u16 h) {
  u32 u = ((u32)h) << 16;
  return __builtin_bit_cast(float, u);
}
__device__ __forceinline__ short8 cvt8(float4_t f0, float4_t f1) {
  short8 v;
  v[0]=(short)f2bf(f0[0]); v[1]=(short)f2bf(f0[1]); v[2]=(short)f2bf(f0[2]); v[3]=(short)f2bf(f0[3]);
  v[4]=(short)f2bf(f1[0]); v[5]=(short)f2bf(f1[1]); v[6]=(short)f2bf(f1[2]); v[7]=(short)f2bf(f1[3]);
  return v;
}

__global__ __launch_bounds__(256) void prep_w(const float* __restrict__ Wr,
                                              const float* __restrict__ Wr2,
                                              const float* __restrict__ Win,
                                              u16* __restrict__ W1b,
                                              u16* __restrict__ W2b,
                                              u16* __restrict__ Winb) {
  const int i = blockIdx.x * 256 + threadIdx.x;   // 0 .. 1048575
  W1b[i] = f2bf(Wr[i]);
  W2b[i] = f2bf(Wr2[i]);
  if (i < 131072) Winb[i] = f2bf(Win[i]);
}

// ext GEMM: ebuf[t][b][n] = sum_k x[b][t][k]*Winb[n][k] + bin[n], bf16 out.
// 4096 WGs x 16 rows; wave covers 4 n-tiles of 64 cols.
__global__ __launch_bounds__(256) void ext_gemm(const float* __restrict__ x,
                                                const u16* __restrict__ Winb,
                                                const float* __restrict__ bin,
                                                u16* __restrict__ ebuf) {
  const int mt = blockIdx.x;                      // 0..4095
  const int tid = threadIdx.x;
  const int wave = tid >> 6, lane = tid & 63, quad = lane >> 4, lm = lane & 15;
  const int m0 = mt << 4;

  short8 a[4];
#pragma unroll
  for (int ks = 0; ks < 4; ++ks) {
    const float* p = x + (m0 + lm) * 128 + (ks * 32 + quad * 8);
    a[ks] = cvt8(*(const float4_t*)p, *(const float4_t*)(p + 4));
  }
#pragma unroll
  for (int i = 0; i < 4; ++i) {
    const int n0 = ((wave << 2) + i) << 6;
    short8 bfr[4][4];
#pragma unroll
    for (int nsub = 0; nsub < 4; ++nsub)
#pragma unroll
      for (int ks = 0; ks < 4; ++ks)
        bfr[nsub][ks] = *(const short8*)(Winb + (n0 + (nsub << 4) + lm) * 128 + ks * 32 + quad * 8);
    float4_t acc[4] = { {0,0,0,0},{0,0,0,0},{0,0,0,0},{0,0,0,0} };
#pragma unroll
    for (int ks = 0; ks < 4; ++ks)
#pragma unroll
      for (int nsub = 0; nsub < 4; ++nsub)
        acc[nsub] = __builtin_amdgcn_mfma_f32_16x16x32_bf16(a[ks], bfr[nsub][ks], acc[nsub], 0, 0, 0);
#pragma unroll
    for (int nsub = 0; nsub < 4; ++nsub) {
      const int n = n0 + (nsub << 4) + lm;
      const float bv = bin[n];
#pragma unroll
      for (int r = 0; r < 4; ++r) {
        const int m = m0 + (quad << 2) + r;
        const int b = m >> 8, t = m & 255;
        ebuf[(((t << 8) | b) << 10) + n] = f2bf(acc[nsub][r] + bv);
      }
    }
  }
}

// Barrier-free pipelined recurrence. 256 WGs x 512 thr. WG = (ns: 64 cols, rb: 4 rows/chain).
// Waves 0-3: stage1 (W1, k-quarter q); waves 4-7: stage2 (W2, k-quarter q).
__global__ __launch_bounds__(512, 2) void rnn_pipe2(
    const u16* __restrict__ ebuf,
    u32* __restrict__ ub0, u32* __restrict__ ub1,
    u32* __restrict__ sb0, u32* __restrict__ sb1,
    const u16* __restrict__ W1b, const u16* __restrict__ W2b,
    const float* __restrict__ b1, const float* __restrict__ b2,
    float* __restrict__ fbuf) {
  __shared__ __align__(16) float Pt[2][4][4][4][68];  // [stage][depth][wave][row][col+pad]
  __shared__ u32 flg[8][16];                          // per-wave monotonic slot counters

  const int tid = threadIdx.x;
  const int w = tid >> 6;
  const int st = w >> 2;                 // 0: stage1, 1: stage2
  const int q = w & 3;                   // k-quarter
  const int lane = tid & 63, quad = lane >> 4, lm = lane & 15;
  const int rsub = lm & 3;               // real row within 4-row block (dup x4)
  const int ns = blockIdx.x & 15, rb = blockIdx.x >> 4;
  const int n0 = ns << 6;

  if (lane == 0) flg[w][0] = 0;
  __syncthreads();                       // one-time init barrier only

  // persistent weights: this stage's matrix, k-quarter q, 64 cols
  short8 wf[4][8];
  {
    const u16* Wm = st ? W2b : W1b;
#pragma unroll
    for (int nsub = 0; nsub < 4; ++nsub)
#pragma unroll
      for (int ks = 0; ks < 8; ++ks)
        wf[nsub][ks] = *(const short8*)(Wm + ((n0 + (nsub << 4) + lm) << 10) + (q << 8) + (ks << 5) + (quad << 3));
  }

  const int rrow = (lane >> 4) & 3;      // reduce row 0..3
  const int rcol = lane & 15;            // reduce col within 16-col chunk
  const float bias = (st ? b2 : b1)[n0 + (q << 4) + rcol];

  u32* const ub[2] = { ub0, ub1 };
  u32* const sb[2] = { sb0, sb1 };

  u64 pf[32];
  if (st) {  // initial prefetch: stage2 slot 0 = s1(c=0,t=0), tag 1
    const u32* ab = sb[0] + (((rb << 2) + rsub) << 10) + (q << 8) + (quad << 3);
#pragma unroll
    for (int ks = 0; ks < 8; ++ks)
#pragma unroll
      for (int i = 0; i < 4; ++i)
        pf[(ks << 2) + i] = __hip_atomic_load((const u64*)(ab + (ks << 5) + (i << 1)),
                                              __ATOMIC_RELAXED, __HIP_MEMORY_SCOPE_AGENT);
  }

  for (int j = 0; j < 1024; ++j) {
    const int c = j & 3, t = j >> 2;
    const int row0 = (c << 6) + (rb << 2);

    // stage-2: e(t+1) plain load (consumed in reduce; latency hidden by slot body)
    float ev = 0.f;
    if (st && t < 255)
      ev = bf2f(ebuf[((((t + 1) << 8) + row0 + rrow) << 10) + n0 + (q << 4) + rcol]);

    // prefetch address for slot j+1
    const int j1 = j + 1;
    const int c1 = j1 & 3, t1 = j1 >> 2;
    const bool do_pf = (j1 < 1024) && (st || j1 >= 4);
    const u32* ab1 = (st ? sb[t1 & 1] : ub[t1 & 1]) +
                     (((c1 << 6) + (rb << 2) + rsub) << 10) + (q << 8) + (quad << 3);

    float4_t acc[4] = { {0,0,0,0},{0,0,0,0},{0,0,0,0},{0,0,0,0} };

    if (!st && t == 0) {                 // stage1 t=0: plain bf16 from ebuf
      const u16* rbp = ebuf + ((row0 + rsub) << 10) + (q << 8) + (quad << 3);
#pragma unroll
      for (int ks = 0; ks < 8; ++ks) {
        const short8 a = *(const short8*)(rbp + (ks << 5));
        if (do_pf) {                     // issue prefetch (j=3 -> slot 4)
#pragma unroll
          for (int i = 0; i < 4; ++i)
            pf[(ks << 2) + i] = __hip_atomic_load((const u64*)(ab1 + (ks << 5) + (i << 1)),
                                                  __ATOMIC_RELAXED, __HIP_MEMORY_SCOPE_AGENT);
        }
#pragma unroll
        for (int nsub = 0; nsub < 4; ++nsub)
          acc[nsub] = __builtin_amdgcn_mfma_f32_16x16x32_bf16(a, wf[nsub][ks], acc[nsub], 0, 0, 0);
      }
    } else {
      const u32 tag = (u32)(st ? (t + 1) : t);
      const u32* ab = (st ? sb[t & 1] : ub[t & 1]) + ((row0 + rsub) << 10) + (q << 8) + (quad << 3);
      for (;;) {                         // validate prefetched data (tags == expected)
        u32 bad = 0;
#pragma unroll
        for (int i = 0; i < 32; ++i)
          bad |= (((u32)pf[i] ^ tag) | ((u32)(pf[i] >> 32) ^ tag)) & 0xffffu;
        if (__all(bad == 0)) break;
        __builtin_amdgcn_s_sleep(1);
#pragma unroll
        for (int ks = 0; ks < 8; ++ks)
#pragma unroll
          for (int i = 0; i < 4; ++i)
            pf[(ks << 2) + i] = __hip_atomic_load((const u64*)(ab + (ks << 5) + (i << 1)),
                                                  __ATOMIC_RELAXED, __HIP_MEMORY_SCOPE_AGENT);
      }
      // per-ks: unpack -> reuse pf quad for j+1 prefetch -> 4 MFMAs (keeps VGPRs ~215)
#pragma unroll
      for (int ks = 0; ks < 8; ++ks) {
        uint4 pk;
        const u64 v0 = pf[(ks << 2) + 0], v1 = pf[(ks << 2) + 1];
        const u64 v2 = pf[(ks << 2) + 2], v3 = pf[(ks << 2) + 3];
        pk.x = ((u32)v0 >> 16) | ((u32)(v0 >> 32) & 0xffff0000u);
        pk.y = ((u32)v1 >> 16) | ((u32)(v1 >> 32) & 0xffff0000u);
        pk.z = ((u32)v2 >> 16) | ((u32)(v2 >> 32) & 0xffff0000u);
        pk.w = ((u32)v3 >> 16) | ((u32)(v3 >> 32) & 0xffff0000u);
        const short8 a = __builtin_bit_cast(short8, pk);
        if (do_pf) {
#pragma unroll
          for (int i = 0; i < 4; ++i)
            pf[(ks << 2) + i] = __hip_atomic_load((const u64*)(ab1 + (ks << 5) + (i << 1)),
                                                  __ATOMIC_RELAXED, __HIP_MEMORY_SCOPE_AGENT);
        }
#pragma unroll
        for (int nsub = 0; nsub < 4; ++nsub)
          acc[nsub] = __builtin_amdgcn_mfma_f32_16x16x32_bf16(a, wf[nsub][ks], acc[nsub], 0, 0, 0);
      }
    }

    // publish k-partials to LDS (quad0 holds real rows), bump flag (lgkmcnt only)
    if (quad == 0) {
#pragma unroll
      for (int nsub = 0; nsub < 4; ++nsub)
#pragma unroll
        for (int r = 0; r < 4; ++r)
          Pt[st][j & 3][q][r][(nsub << 4) + lm] = acc[nsub][r];
    }
    asm volatile("s_waitcnt lgkmcnt(0)" ::: "memory");
    if (lane == 0) *(volatile u32*)&flg[w][0] = (u32)(j + 1);

    // reduce chunk q: spin on 4 sibling flags (LDS), sum, bias, relu, (+e), tagged store
    {
      const int fb = st << 2;
#pragma unroll
      for (int w2 = 0; w2 < 4; ++w2)
        while (*(volatile u32*)&flg[fb + w2][0] < (u32)(j + 1))
          __builtin_amdgcn_s_sleep(1);
      asm volatile("" ::: "memory");
      float s = bias;
#pragma unroll
      for (int w2 = 0; w2 < 4; ++w2)
        s += Pt[st][j & 3][w2][rrow][(q << 4) + rcol];
      s = s > 0.f ? s : 0.f;
      const int grow = row0 + rrow;
      const int gcol = n0 + (q << 4) + rcol;
      if (!st) {
        const u32 wd = ((u32)f2bf(s) << 16) | (u32)(t + 1);
        __hip_atomic_store(sb[t & 1] + (grow << 10) + gcol, wd,
                           __ATOMIC_RELAXED, __HIP_MEMORY_SCOPE_AGENT);
      } else if (t < 255) {
        s += ev;
        const u32 wd = ((u32)f2bf(s) << 16) | (u32)(t + 1);
        __hip_atomic_store(ub[(t + 1) & 1] + (grow << 10) + gcol, wd,
                           __ATOMIC_RELAXED, __HIP_MEMORY_SCOPE_AGENT);
      } else {
        fbuf[(grow << 10) + gcol] = s;   // final state fp32 (kernel-end flush)
      }
    }
  }
}

__global__ __launch_bounds__(256) void bcast(const float* __restrict__ fbuf,
                                             float* __restrict__ out) {
  const int idx4 = blockIdx.x * 256 + threadIdx.x;   // 0..16777215 float4s
  const int b = idx4 >> 16;
  const int s4 = idx4 & 255;
  const float4_t v = *(const float4_t*)(fbuf + (b << 10) + (s4 << 2));
  *(float4_t*)(out + ((size_t)idx4 << 2)) = v;
}

extern "C" void kernel_launch(void* const* d_in, const int* in_sizes, int n_in,
                              void* d_out, int out_size, void* d_ws, size_t ws_size,
                              hipStream_t stream) {
  const float* x     = (const float*)d_in[0];
  const float* Win   = (const float*)d_in[1];
  const float* bin   = (const float*)d_in[2];
  const float* Wrec  = (const float*)d_in[3];
  const float* brec  = (const float*)d_in[4];
  const float* Wrec2 = (const float*)d_in[5];
  const float* brec2 = (const float*)d_in[6];
  float* out = (float*)d_out;

  char* ws = (char*)d_ws;
  u32* ub0 = (u32*)(ws);                  // 1 MB tagged u, even t
  u32* ub1 = (u32*)(ws + (1u << 20));     // 1 MB tagged u, odd t
  u32* sb0 = (u32*)(ws + (2u << 20));     // 1 MB tagged s1, even t
  u32* sb1 = (u32*)(ws + (3u << 20));     // 1 MB tagged s1, odd t
  float* fbuf = (float*)(ws + (4u << 20));// 1 MB final state
  // scratch inside d_out (268 MB): all dead before bcast overwrites
  u16* ebuf = (u16*)d_out;                          // 128 MB
  u16* Winb = (u16*)((char*)d_out + (192u << 20));  // 256 KB
  u16* W1b  = (u16*)((char*)d_out + (200u << 20));  // 2 MB
  u16* W2b  = (u16*)((char*)d_out + (208u << 20));  // 2 MB
  // No tag init needed: expected tags 1..256; 0xAAAA poison never matches.

  prep_w<<<4096, 256, 0, stream>>>(Wrec, Wrec2, Win, W1b, W2b, Winb);
  ext_gemm<<<4096, 256, 0, stream>>>(x, Winb, bin, ebuf);

  void* args[] = { (void*)&ebuf, (void*)&ub0, (void*)&ub1, (void*)&sb0, (void*)&sb1,
                   (void*)&W1b, (void*)&W2b, (void*)&brec, (void*)&brec2, (void*)&fbuf };
  (void)hipLaunchCooperativeKernel(reinterpret_cast<void*>(rnn_pipe2),
                                   dim3(256), dim3(512), args, 0, stream);

  bcast<<<65536, 256, 0, stream>>>(fbuf, out);
}